// Round 8
// baseline (25.860 us; speedup 1.0000x reference)
//
#include <hip/hip_runtime.h>

// KroneckerLoss: per-row reductions over 4 fp32 [8192,1024] arrays + scalar MSE.
// a = sum(obs1_row); c = dot(obs2_row, [1,-1,...]); h1 = sum(hyp1_row); h2 = sum(hyp2_row)
// s1 = a*h1*c, s2 = a*h2*c; t1 = (label==1 ? 1 : -1), t2 = -t1
// out = sum_rows 0.5*((s1-t1)^2 + (s2-t2)^2)
//
// R8: R7 + deeper per-wave MLP. Every prior round compiled to 36 VGPR
// (~4-5 loads in flight). __launch_bounds__(64, 8) keeps 8 waves/SIMD
// (32/CU, same TLP) but raises the VGPR cap to 64, and an explicit
// 2-stage x 8-load software pipeline keeps ~8 KB/wave in flight.
// Structure otherwise identical: 8192 x 1-wave blocks, nt loads,
// partials -> d_ws, separate finish kernel (atomics ruled out: ~9ns each
// same-address serialized, R1 vs R5).

typedef float vf4 __attribute__((ext_vector_type(4)));

constexpr int kB = 8192;
constexpr int kD = 1024;
constexpr int kChunks = (kD / 4) / 64;       // 4 float4 loads per lane per array

__global__ __launch_bounds__(64, 8) void kron_loss_kernel(
    const float* __restrict__ obs1, const float* __restrict__ obs2,
    const float* __restrict__ hyp1, const float* __restrict__ hyp2,
    const int* __restrict__ labels, float* __restrict__ partials)
{
    const int lane = threadIdx.x;            // 64-thread block = 1 wave
    const int row  = blockIdx.x;
    const size_t base = (size_t)row * kD;

    const vf4* o1 = reinterpret_cast<const vf4*>(obs1 + base);
    const vf4* o2 = reinterpret_cast<const vf4*>(obs2 + base);
    const vf4* h1 = reinterpret_cast<const vf4*>(hyp1 + base);
    const vf4* h2 = reinterpret_cast<const vf4*>(hyp2 + base);

    // 2-stage software pipeline, 8 vf4 in flight (32 VGPRs of data).
    vf4 p0[4], p1[4];
    {
        const int i0 = lane;            // k=0
        const int i1 = lane + 64;       // k=1
        p0[0] = __builtin_nontemporal_load(&o1[i0]);
        p0[1] = __builtin_nontemporal_load(&o2[i0]);
        p0[2] = __builtin_nontemporal_load(&h1[i0]);
        p0[3] = __builtin_nontemporal_load(&h2[i0]);
        p1[0] = __builtin_nontemporal_load(&o1[i1]);
        p1[1] = __builtin_nontemporal_load(&o2[i1]);
        p1[2] = __builtin_nontemporal_load(&h1[i1]);
        p1[3] = __builtin_nontemporal_load(&h2[i1]);
    }

    float a = 0.f, c = 0.f, b1 = 0.f, b2 = 0.f;

    // consume p0 (k=0), refill p0 with k=2
    {
        vf4 v1 = p0[0], v2 = p0[1], w1 = p0[2], w2 = p0[3];
        const int i2 = lane + 128;
        p0[0] = __builtin_nontemporal_load(&o1[i2]);
        p0[1] = __builtin_nontemporal_load(&o2[i2]);
        p0[2] = __builtin_nontemporal_load(&h1[i2]);
        p0[3] = __builtin_nontemporal_load(&h2[i2]);
        a  += (v1.x + v1.y) + (v1.z + v1.w);
        c  += (v2.x - v2.y) + (v2.z - v2.w);
        b1 += (w1.x + w1.y) + (w1.z + w1.w);
        b2 += (w2.x + w2.y) + (w2.z + w2.w);
    }
    // consume p1 (k=1), refill p1 with k=3
    {
        vf4 v1 = p1[0], v2 = p1[1], w1 = p1[2], w2 = p1[3];
        const int i3 = lane + 192;
        p1[0] = __builtin_nontemporal_load(&o1[i3]);
        p1[1] = __builtin_nontemporal_load(&o2[i3]);
        p1[2] = __builtin_nontemporal_load(&h1[i3]);
        p1[3] = __builtin_nontemporal_load(&h2[i3]);
        a  += (v1.x + v1.y) + (v1.z + v1.w);
        c  += (v2.x - v2.y) + (v2.z - v2.w);
        b1 += (w1.x + w1.y) + (w1.z + w1.w);
        b2 += (w2.x + w2.y) + (w2.z + w2.w);
    }
    // drain p0 (k=2)
    {
        vf4 v1 = p0[0], v2 = p0[1], w1 = p0[2], w2 = p0[3];
        a  += (v1.x + v1.y) + (v1.z + v1.w);
        c  += (v2.x - v2.y) + (v2.z - v2.w);
        b1 += (w1.x + w1.y) + (w1.z + w1.w);
        b2 += (w2.x + w2.y) + (w2.z + w2.w);
    }
    // drain p1 (k=3)
    {
        vf4 v1 = p1[0], v2 = p1[1], w1 = p1[2], w2 = p1[3];
        a  += (v1.x + v1.y) + (v1.z + v1.w);
        c  += (v2.x - v2.y) + (v2.z - v2.w);
        b1 += (w1.x + w1.y) + (w1.z + w1.w);
        b2 += (w2.x + w2.y) + (w2.z + w2.w);
    }

    // 64-lane butterfly; 4 independent chains give ILP.
    #pragma unroll
    for (int off = 32; off > 0; off >>= 1) {
        a  += __shfl_down(a,  off);
        c  += __shfl_down(c,  off);
        b1 += __shfl_down(b1, off);
        b2 += __shfl_down(b2, off);
    }

    if (lane == 0) {
        const float t1 = (labels[row] == 1) ? 1.f : -1.f;  // t2 = -t1
        const float ac = a * c;
        const float s1 = ac * b1;
        const float s2 = ac * b2;
        const float d1 = s1 - t1;
        const float d2 = s2 + t1;
        partials[row] = 0.5f * (d1 * d1 + d2 * d2);
    }
}

// Reduce kB (=8192) partials -> out[0]. One 256-thread block.
__global__ __launch_bounds__(256) void kron_loss_finish(
    const float* __restrict__ partials, float* __restrict__ out)
{
    const int tid  = threadIdx.x;
    const int wave = tid >> 6;
    const int lane = tid & 63;
    const vf4* p4 = reinterpret_cast<const vf4*>(partials);
    // 8192 floats = 2048 float4; 256 threads x 8 float4
    float s = 0.f;
    #pragma unroll
    for (int k = 0; k < 8; ++k) {
        vf4 u = p4[tid + 256 * k];
        s += (u.x + u.y) + (u.z + u.w);
    }
    #pragma unroll
    for (int off = 32; off > 0; off >>= 1) s += __shfl_down(s, off);
    __shared__ float ps[4];
    if (lane == 0) ps[wave] = s;
    __syncthreads();
    if (tid == 0) out[0] = (ps[0] + ps[1]) + (ps[2] + ps[3]);
}

extern "C" void kernel_launch(void* const* d_in, const int* in_sizes, int n_in,
                              void* d_out, int out_size, void* d_ws, size_t ws_size,
                              hipStream_t stream) {
    const float* obs1   = (const float*)d_in[0];
    const float* obs2   = (const float*)d_in[1];
    const float* hyp1   = (const float*)d_in[2];
    const float* hyp2   = (const float*)d_in[3];
    const int*   labels = (const int*)d_in[4];
    float* out      = (float*)d_out;
    float* partials = (float*)d_ws;   // 8192 floats, fully overwritten every call

    kron_loss_kernel<<<kB, 64, 0, stream>>>(obs1, obs2, hyp1, hyp2, labels, partials);
    kron_loss_finish<<<1, 256, 0, stream>>>(partials, out);
}